// Round 2
// baseline (721.954 us; speedup 1.0000x reference)
//
#include <hip/hip_runtime.h>
#include <stdint.h>

#define BN 4
#define CD 256
#define ND 4096
#define NK 32          // key-tile size in attention
#define NITER (ND / NK)

typedef unsigned short u16;
typedef short bfrag __attribute__((ext_vector_type(8)));  // 8 bf16 = 4 VGPR
typedef float ffrag __attribute__((ext_vector_type(4)));  // MFMA C/D frag

__device__ __forceinline__ float bf2f(u16 u) {
  union { unsigned int i; float f; } v;
  v.i = ((unsigned int)u) << 16;
  return v.f;
}
__device__ __forceinline__ u16 f2bf(float f) {
  union { float f; unsigned int i; } v;
  v.f = f;
  return (u16)((v.i + 0x7FFFu + ((v.i >> 16) & 1u)) >> 16);  // RNE
}

// ---------- convert fp32 weights [256][256] x3 -> bf16 ----------
__global__ __launch_bounds__(256) void k_cvtW(
    const float* __restrict__ Wq, const float* __restrict__ Wk,
    const float* __restrict__ Wv, u16* __restrict__ wb) {
  int m = blockIdx.y;
  const float* src = (m == 0) ? Wq : ((m == 1) ? Wk : Wv);
  u16* dst = wb + (size_t)m * CD * CD;
  int i = (blockIdx.x * 256 + threadIdx.x) * 4;  // grid.x=64 -> 65536 floats
  float4 v = *(const float4*)(src + i);
  ushort4 o;
  o.x = f2bf(v.x); o.y = f2bf(v.y); o.z = f2bf(v.z); o.w = f2bf(v.w);
  *(ushort4*)(dst + i) = o;
}

// ---------- transpose+cast [B][C][N] fp32 -> [B][N][C] bf16 ----------
__global__ __launch_bounds__(256) void k_transpose(
    const float* __restrict__ x, const float* __restrict__ y,
    u16* __restrict__ xT, u16* __restrict__ yT) {
  __shared__ alignas(16) u16 tile[64][72];  // stride 144B: 16B-mult, not 128B-mult
  int n0 = blockIdx.x * 64, c0 = blockIdx.y * 64, bz = blockIdx.z;
  const float* src = (bz < BN) ? x : y;
  u16* dst = (bz < BN) ? xT : yT;
  int b = bz & (BN - 1);
  src += (size_t)b * CD * ND;
  dst += (size_t)b * ND * CD;
  int t = threadIdx.x;
#pragma unroll
  for (int it = 0; it < 4; ++it) {
    int idx = it * 256 + t;      // 0..1023
    int ci = idx >> 4;           // 0..63
    int nj = (idx & 15) * 4;     // 0..60
    float4 v = *(const float4*)(src + (size_t)(c0 + ci) * ND + n0 + nj);
    tile[nj + 0][ci] = f2bf(v.x);
    tile[nj + 1][ci] = f2bf(v.y);
    tile[nj + 2][ci] = f2bf(v.z);
    tile[nj + 3][ci] = f2bf(v.w);
  }
  __syncthreads();
#pragma unroll
  for (int it = 0; it < 2; ++it) {
    int idx = it * 256 + t;      // 0..511
    int ni = idx >> 3;           // 0..63
    int cj = (idx & 7) * 8;      // 0..56
    uint4 v = *(const uint4*)&tile[ni][cj];
    *(uint4*)(dst + (size_t)(n0 + ni) * CD + c0 + cj) = v;
  }
}

// ---------- generic projection GEMM (bf16 in, bf16 out, fp32 bias) ----------
// C[m][n] = sum_k A[m][k]*Bw[n][k] + bias   (K=256, A,Bw k-contiguous)
// bias_per_row=0: bias[n];  =1: bias[m]
__global__ __launch_bounds__(256, 2) void k_proj(
    const u16* __restrict__ A, const u16* __restrict__ Bw,
    const float* __restrict__ bias, u16* __restrict__ C,
    int ldc, int bias_per_row, size_t aBS, size_t bBS, size_t cBS) {
  __shared__ alignas(16) u16 As[64][264];  // 33,792 B
  __shared__ alignas(16) u16 Bs[64][136];  // 17,408 B (K staged in 2 halves)
  int m0 = blockIdx.x * 64, n0 = blockIdx.y * 64;
  size_t z = blockIdx.z;
  A += z * aBS; Bw += z * bBS; C += z * cBS;
  int t = threadIdx.x, w = t >> 6, l = t & 63;
  int lane16 = l & 15, quad = l >> 4;
#pragma unroll
  for (int it = 0; it < 8; ++it) {
    int c = it * 256 + t;
    int r = c >> 5, co = (c & 31) * 8;
    *(uint4*)&As[r][co] = *(const uint4*)(A + (size_t)(m0 + r) * CD + co);
  }
  ffrag acc[4];
#pragma unroll
  for (int tt = 0; tt < 4; ++tt) acc[tt] = ffrag{0.f, 0.f, 0.f, 0.f};
#pragma unroll
  for (int half = 0; half < 2; ++half) {
    if (half) __syncthreads();  // prior MFMA reads of Bs done
#pragma unroll
    for (int it = 0; it < 4; ++it) {
      int c = it * 256 + t;
      int r = c >> 4, co = (c & 15) * 8;  // 64 rows x 128 k
      *(uint4*)&Bs[r][co] =
          *(const uint4*)(Bw + (size_t)(n0 + r) * CD + half * 128 + co);
    }
    __syncthreads();
#pragma unroll
    for (int kc = 0; kc < 4; ++kc) {
      bfrag af = *(const bfrag*)&As[w * 16 + lane16][half * 128 + kc * 32 + quad * 8];
#pragma unroll
      for (int tt = 0; tt < 4; ++tt) {
        bfrag bfr = *(const bfrag*)&Bs[tt * 16 + lane16][kc * 32 + quad * 8];
        acc[tt] = __builtin_amdgcn_mfma_f32_16x16x32_bf16(af, bfr, acc[tt], 0, 0, 0);
      }
    }
  }
  // epilogue: row = m0 + w*16 + quad*4 + r, col = n0 + tt*16 + lane16
#pragma unroll
  for (int tt = 0; tt < 4; ++tt) {
    int col = n0 + tt * 16 + lane16;
    float bcol = bias_per_row ? 0.f : bias[col];
#pragma unroll
    for (int r = 0; r < 4; ++r) {
      int row = m0 + w * 16 + quad * 4 + r;
      float bb = bias_per_row ? bias[row] : bcol;
      C[(size_t)row * ldc + col] = f2bf(acc[tt][r] + bb);
    }
  }
}

// ---------- flash attention + residual; x,out fp32; Q,K,Vt bf16 ----------
// Q,K: [B*N][C] (k-contiguous in d); Vt: [B][C][N] (k-contiguous in key)
union SmemU {
  struct {
    u16 Ks[NK][264];        // 16,896 B
    u16 Vs[CD][NK + 8];     // 20,480 B
    u16 Ps[4][16][NK + 8];  //  5,120 B
  } a;
  u16 ot[CD][72];           // 36,864 B  epilogue O^T staging (bf16)
};

__global__ __launch_bounds__(256, 2) void k_attn(
    const u16* __restrict__ Q, const u16* __restrict__ K,
    const u16* __restrict__ Vt, const float* __restrict__ x,
    float* __restrict__ out) {
  __shared__ alignas(16) SmemU sm;
  int b = blockIdx.y, q0 = blockIdx.x * 64;
  int t = threadIdx.x, w = t >> 6, l = t & 63;
  int lane16 = l & 15, quad = l >> 4;
  const float scale = 0.0625f;  // 256^-0.5

  // Q frags: A-layout A[m=lane16][k=quad*8+j], rows q0 + w*16 + lane16
  bfrag qf[8];
  const u16* Qrow = Q + ((size_t)b * ND + q0 + w * 16 + lane16) * CD;
#pragma unroll
  for (int kc = 0; kc < 8; ++kc)
    qf[kc] = *(const bfrag*)(Qrow + kc * 32 + quad * 8);

  ffrag o[16];
#pragma unroll
  for (int i = 0; i < 16; ++i) o[i] = ffrag{0.f, 0.f, 0.f, 0.f};
  float m_i[4] = {-1e30f, -1e30f, -1e30f, -1e30f};
  float l_i[4] = {0.f, 0.f, 0.f, 0.f};

  const u16* Kb = K + (size_t)b * ND * CD;
  const u16* Vb = Vt + (size_t)b * CD * ND;

  uint4 kreg[4], vreg[4];
  auto load_tiles = [&](int kt2) {
    const u16* Kt = Kb + (size_t)kt2 * NK * CD;
    const u16* Vtt = Vb + kt2 * NK;
#pragma unroll
    for (int it = 0; it < 4; ++it) {
      int c = it * 256 + t;
      kreg[it] = *(const uint4*)(Kt + (size_t)(c >> 5) * CD + (c & 31) * 8);
      vreg[it] = *(const uint4*)(Vtt + (size_t)(c >> 2) * ND + (c & 3) * 8);
    }
  };

  load_tiles(0);
  for (int kt = 0; kt < NITER; ++kt) {
    __syncthreads();  // prior compute done reading LDS
#pragma unroll
    for (int it = 0; it < 4; ++it) {
      int c = it * 256 + t;
      *(uint4*)&sm.a.Ks[c >> 5][(c & 31) * 8] = kreg[it];
      *(uint4*)&sm.a.Vs[c >> 2][(c & 3) * 8] = vreg[it];
    }
    __syncthreads();
    if (kt + 1 < NITER) load_tiles(kt + 1);  // overlaps compute below

    // S = Q K^T (2 col-tiles of 16 keys)
    ffrag s[2];
    s[0] = ffrag{0.f, 0.f, 0.f, 0.f};
    s[1] = ffrag{0.f, 0.f, 0.f, 0.f};
#pragma unroll
    for (int kc = 0; kc < 8; ++kc) {
      bfrag k0 = *(const bfrag*)&sm.a.Ks[lane16][kc * 32 + quad * 8];
      bfrag k1 = *(const bfrag*)&sm.a.Ks[16 + lane16][kc * 32 + quad * 8];
      s[0] = __builtin_amdgcn_mfma_f32_16x16x32_bf16(qf[kc], k0, s[0], 0, 0, 0);
      s[1] = __builtin_amdgcn_mfma_f32_16x16x32_bf16(qf[kc], k1, s[1], 0, 0, 0);
    }

    // online softmax; row = quad*4 + r; stats replicated across quad's 16 lanes
#pragma unroll
    for (int r = 0; r < 4; ++r) {
      float v0 = fmaxf(s[0][r], s[1][r]) * scale;
#pragma unroll
      for (int off = 1; off < 16; off <<= 1) v0 = fmaxf(v0, __shfl_xor(v0, off, 64));
      float mn = fmaxf(m_i[r], v0);
      float al = __expf(m_i[r] - mn);
      m_i[r] = mn;
      float rs = 0.f;
#pragma unroll
      for (int tt = 0; tt < 2; ++tt) {
        float p = __expf(s[tt][r] * scale - mn);
        s[tt][r] = p;
        rs += p;
      }
#pragma unroll
      for (int off = 1; off < 16; off <<= 1) rs += __shfl_xor(rs, off, 64);
      l_i[r] = l_i[r] * al + rs;
#pragma unroll
      for (int dt = 0; dt < 16; ++dt) o[dt][r] *= al;
    }

    // P (C/D layout) -> LDS [qrow][key]
#pragma unroll
    for (int tt = 0; tt < 2; ++tt)
#pragma unroll
      for (int r = 0; r < 4; ++r)
        sm.a.Ps[w][quad * 4 + r][tt * 16 + lane16] = f2bf(s[tt][r]);
    __syncthreads();

    // O += P V  (one 32-key MFMA step, 16 d-tiles)
    bfrag pf = *(const bfrag*)&sm.a.Ps[w][lane16][quad * 8];
#pragma unroll
    for (int dt = 0; dt < 16; ++dt) {
      bfrag vf = *(const bfrag*)&sm.a.Vs[dt * 16 + lane16][quad * 8];
      o[dt] = __builtin_amdgcn_mfma_f32_16x16x32_bf16(pf, vf, o[dt], 0, 0, 0);
    }
  }

  __syncthreads();
  // O/l -> transposed bf16 staging ot[d][q_local]
#pragma unroll
  for (int dt = 0; dt < 16; ++dt)
#pragma unroll
    for (int r = 0; r < 4; ++r)
      sm.ot[dt * 16 + lane16][w * 16 + quad * 4 + r] = f2bf(o[dt][r] / l_i[r]);
  __syncthreads();
  // out[b][d][q0+..] = x + O^T   (fp32, coalesced)
#pragma unroll
  for (int it = 0; it < 8; ++it) {
    int c = it * 256 + t;
    int d = c >> 3, co = (c & 7) * 8;
    size_t g = ((size_t)b * CD + d) * ND + q0 + co;
    float4 x0 = *(const float4*)(x + g);
    float4 x1 = *(const float4*)(x + g + 4);
    float4 o0, o1;
    o0.x = x0.x + bf2f(sm.ot[d][co + 0]);
    o0.y = x0.y + bf2f(sm.ot[d][co + 1]);
    o0.z = x0.z + bf2f(sm.ot[d][co + 2]);
    o0.w = x0.w + bf2f(sm.ot[d][co + 3]);
    o1.x = x1.x + bf2f(sm.ot[d][co + 4]);
    o1.y = x1.y + bf2f(sm.ot[d][co + 5]);
    o1.z = x1.z + bf2f(sm.ot[d][co + 6]);
    o1.w = x1.w + bf2f(sm.ot[d][co + 7]);
    *(float4*)(out + g) = o0;
    *(float4*)(out + g + 4) = o1;
  }
}

extern "C" void kernel_launch(void* const* d_in, const int* in_sizes, int n_in,
                              void* d_out, int out_size, void* d_ws, size_t ws_size,
                              hipStream_t stream) {
  const float* x  = (const float*)d_in[0];
  const float* y  = (const float*)d_in[1];
  const float* Wq = (const float*)d_in[2];
  const float* bq = (const float*)d_in[3];
  const float* Wk = (const float*)d_in[4];
  const float* bk = (const float*)d_in[5];
  const float* Wv = (const float*)d_in[6];
  const float* bv = (const float*)d_in[7];
  float* out = (float*)d_out;
  u16* ws = (u16*)d_ws;
  const size_t WSZ = (size_t)3 * CD * CD;     // 196,608 u16 (bf16 weights)
  const size_t SZ  = (size_t)BN * ND * CD;    // 4,194,304 u16 per tensor
  u16* wB = ws;                // Wq,Wk,Wv bf16
  u16* xT = ws + WSZ;          // [B][N][C]
  u16* yT = xT + SZ;           // [B][N][C]
  u16* Qb = yT + SZ;           // [B*N][C]
  u16* Kb = Qb + SZ;           // [B*N][C]
  u16* Vb = Kb + SZ;           // [B][C][N] (V transposed)
  // total ws use: ~40.4 MB

  k_cvtW<<<dim3(64, 3), 256, 0, stream>>>(Wq, Wk, Wv, wB);
  k_transpose<<<dim3(ND / 64, CD / 64, BN * 2), 256, 0, stream>>>(x, y, xT, yT);
  k_proj<<<dim3(BN * ND / 64, CD / 64, 1), 256, 0, stream>>>(
      xT, wB, bq, Qb, CD, 0, (size_t)0, (size_t)0, (size_t)0);
  k_proj<<<dim3(BN * ND / 64, CD / 64, 1), 256, 0, stream>>>(
      yT, wB + (size_t)CD * CD, bk, Kb, CD, 0, (size_t)0, (size_t)0, (size_t)0);
  k_proj<<<dim3(CD / 64, ND / 64, BN), 256, 0, stream>>>(
      wB + (size_t)2 * CD * CD, yT, bv, Vb, ND, 1,
      (size_t)0, (size_t)((size_t)ND * CD), (size_t)((size_t)CD * ND));
  k_attn<<<dim3(ND / 64, BN), 256, 0, stream>>>(Qb, Kb, Vb, x, out);
}

// Round 3
// 489.682 us; speedup vs baseline: 1.4743x; 1.4743x over previous
//
#include <hip/hip_runtime.h>
#include <stdint.h>

#define BN 4
#define CD 256
#define ND 4096
#define NK 32            // key-tile size in attention
#define NSPLIT 2         // split-K factor (grid.z)
#define NITER2 (ND / NSPLIT / NK)   // 64 iterations per block

typedef unsigned short u16;
typedef short bfrag __attribute__((ext_vector_type(8)));  // 8 bf16 = 4 VGPR
typedef float ffrag __attribute__((ext_vector_type(4)));  // MFMA C/D frag

__device__ __forceinline__ float bf2f(u16 u) {
  union { unsigned int i; float f; } v;
  v.i = ((unsigned int)u) << 16;
  return v.f;
}
__device__ __forceinline__ u16 f2bf(float f) {
  union { float f; unsigned int i; } v;
  v.f = f;
  return (u16)((v.i + 0x7FFFu + ((v.i >> 16) & 1u)) >> 16);  // RNE
}

// ---------- convert fp32 weights [256][256] x3 -> bf16 ----------
__global__ __launch_bounds__(256) void k_cvtW(
    const float* __restrict__ Wq, const float* __restrict__ Wk,
    const float* __restrict__ Wv, u16* __restrict__ wb) {
  int m = blockIdx.y;
  const float* src = (m == 0) ? Wq : ((m == 1) ? Wk : Wv);
  u16* dst = wb + (size_t)m * CD * CD;
  int i = (blockIdx.x * 256 + threadIdx.x) * 4;
  float4 v = *(const float4*)(src + i);
  ushort4 o;
  o.x = f2bf(v.x); o.y = f2bf(v.y); o.z = f2bf(v.z); o.w = f2bf(v.w);
  *(ushort4*)(dst + i) = o;
}

// ---------- transpose+cast [B][C][N] fp32 -> [B][N][C] bf16 ----------
__global__ __launch_bounds__(256) void k_transpose(
    const float* __restrict__ x, const float* __restrict__ y,
    u16* __restrict__ xT, u16* __restrict__ yT) {
  __shared__ alignas(16) u16 tile[64][72];
  int n0 = blockIdx.x * 64, c0 = blockIdx.y * 64, bz = blockIdx.z;
  const float* src = (bz < BN) ? x : y;
  u16* dst = (bz < BN) ? xT : yT;
  int b = bz & (BN - 1);
  src += (size_t)b * CD * ND;
  dst += (size_t)b * ND * CD;
  int t = threadIdx.x;
#pragma unroll
  for (int it = 0; it < 4; ++it) {
    int idx = it * 256 + t;
    int ci = idx >> 4;
    int nj = (idx & 15) * 4;
    float4 v = *(const float4*)(src + (size_t)(c0 + ci) * ND + n0 + nj);
    tile[nj + 0][ci] = f2bf(v.x);
    tile[nj + 1][ci] = f2bf(v.y);
    tile[nj + 2][ci] = f2bf(v.z);
    tile[nj + 3][ci] = f2bf(v.w);
  }
  __syncthreads();
#pragma unroll
  for (int it = 0; it < 2; ++it) {
    int idx = it * 256 + t;
    int ni = idx >> 3;
    int cj = (idx & 7) * 8;
    uint4 v = *(const uint4*)&tile[ni][cj];
    *(uint4*)(dst + (size_t)(n0 + ni) * CD + c0 + cj) = v;
  }
}

// ---------- projection GEMM (bf16 in/out, fp32 bias) ----------
// C[m][n] = sum_k A[m][k]*Bw[n][k] + bias
// biasA for z==0, biasB for z>=1 (QK-merged mode); bias_per_row selects axis
__global__ __launch_bounds__(256, 2) void k_proj(
    const u16* __restrict__ A, const u16* __restrict__ Bw,
    const float* __restrict__ biasA, const float* __restrict__ biasB,
    u16* __restrict__ C, int ldc, int bias_per_row,
    size_t aBS, size_t bBS, size_t cBS) {
  __shared__ alignas(16) u16 As[64][264];
  __shared__ alignas(16) u16 Bs[64][136];
  int m0 = blockIdx.x * 64, n0 = blockIdx.y * 64;
  size_t z = blockIdx.z;
  const float* bias = (z == 0) ? biasA : biasB;
  A += z * aBS; Bw += z * bBS; C += z * cBS;
  int t = threadIdx.x, w = t >> 6, l = t & 63;
  int lane16 = l & 15, quad = l >> 4;
#pragma unroll
  for (int it = 0; it < 8; ++it) {
    int c = it * 256 + t;
    int r = c >> 5, co = (c & 31) * 8;
    *(uint4*)&As[r][co] = *(const uint4*)(A + (size_t)(m0 + r) * CD + co);
  }
  ffrag acc[4];
#pragma unroll
  for (int tt = 0; tt < 4; ++tt) acc[tt] = ffrag{0.f, 0.f, 0.f, 0.f};
#pragma unroll
  for (int half = 0; half < 2; ++half) {
    if (half) __syncthreads();
#pragma unroll
    for (int it = 0; it < 4; ++it) {
      int c = it * 256 + t;
      int r = c >> 4, co = (c & 15) * 8;
      *(uint4*)&Bs[r][co] =
          *(const uint4*)(Bw + (size_t)(n0 + r) * CD + half * 128 + co);
    }
    __syncthreads();
#pragma unroll
    for (int kc = 0; kc < 4; ++kc) {
      bfrag af = *(const bfrag*)&As[w * 16 + lane16][half * 128 + kc * 32 + quad * 8];
#pragma unroll
      for (int tt = 0; tt < 4; ++tt) {
        bfrag bfr = *(const bfrag*)&Bs[tt * 16 + lane16][kc * 32 + quad * 8];
        acc[tt] = __builtin_amdgcn_mfma_f32_16x16x32_bf16(af, bfr, acc[tt], 0, 0, 0);
      }
    }
  }
#pragma unroll
  for (int tt = 0; tt < 4; ++tt) {
    int col = n0 + tt * 16 + lane16;
    float bcol = bias_per_row ? 0.f : bias[col];
#pragma unroll
    for (int r = 0; r < 4; ++r) {
      int row = m0 + w * 16 + quad * 4 + r;
      float bb = bias_per_row ? bias[row] : bcol;
      C[(size_t)row * ldc + col] = f2bf(acc[tt][r] + bb);
    }
  }
}

// ---------- flash attention, split-K partials, fixed-max softmax ----------
// Q,K: [B*N][C]; Vt: [B][C][N]. Block z handles keys [z*2048, z*2048+2048).
// Writes unnormalized O (bf16, [z][B][C][N] layout via Opart+z*B*C*N handled
// by caller passing base) and row sums Lpart[z][B][N].
union SmemU {
  struct {
    u16 Ks[NK][264];        // 16,896 B
    u16 Vs[CD][NK + 8];     // 20,480 B
    u16 Ps[4][16][NK + 8];  //  5,120 B
  } a;
  u16 ot[CD][72];           // 36,864 B  epilogue O^T staging
};

__global__ __launch_bounds__(256, 2) void k_attn(
    const u16* __restrict__ Q, const u16* __restrict__ K,
    const u16* __restrict__ Vt, u16* __restrict__ O0,
    u16* __restrict__ O1, float* __restrict__ Lpart) {
  __shared__ alignas(16) SmemU sm;
  int b = blockIdx.y, q0 = blockIdx.x * 64, z = blockIdx.z;
  int t = threadIdx.x, w = t >> 6, l = t & 63;
  int lane16 = l & 15, quad = l >> 4;
  const float scale = 0.0625f;  // 256^-0.5

  // Q frags: A-layout, rows q0 + w*16 + lane16
  bfrag qf[8];
  const u16* Qrow = Q + ((size_t)b * ND + q0 + w * 16 + lane16) * CD;
#pragma unroll
  for (int kc = 0; kc < 8; ++kc)
    qf[kc] = *(const bfrag*)(Qrow + kc * 32 + quad * 8);

  ffrag o[16];
#pragma unroll
  for (int i = 0; i < 16; ++i) o[i] = ffrag{0.f, 0.f, 0.f, 0.f};
  float lsum[4] = {0.f, 0.f, 0.f, 0.f};

  const u16* Kb = K + ((size_t)b * ND + z * (ND / NSPLIT)) * CD;
  const u16* Vb = Vt + (size_t)b * CD * ND + z * (ND / NSPLIT);

  uint4 kreg[4], vreg[4];
  auto load_tiles = [&](int kt2) {
    const u16* Kt = Kb + (size_t)kt2 * NK * CD;
    const u16* Vtt = Vb + kt2 * NK;
#pragma unroll
    for (int it = 0; it < 4; ++it) {
      int c = it * 256 + t;
      kreg[it] = *(const uint4*)(Kt + (size_t)(c >> 5) * CD + (c & 31) * 8);
      vreg[it] = *(const uint4*)(Vtt + (size_t)(c >> 2) * ND + (c & 3) * 8);
    }
  };

  load_tiles(0);
  for (int kt = 0; kt < NITER2; ++kt) {
    __syncthreads();  // prior compute done reading Ks/Vs
#pragma unroll
    for (int it = 0; it < 4; ++it) {
      int c = it * 256 + t;
      *(uint4*)&sm.a.Ks[c >> 5][(c & 31) * 8] = kreg[it];
      *(uint4*)&sm.a.Vs[c >> 2][(c & 3) * 8] = vreg[it];
    }
    __syncthreads();
    if (kt + 1 < NITER2) load_tiles(kt + 1);  // overlaps compute below

    // S = Q K^T (2 col-tiles of 16 keys)
    ffrag s[2];
    s[0] = ffrag{0.f, 0.f, 0.f, 0.f};
    s[1] = ffrag{0.f, 0.f, 0.f, 0.f};
#pragma unroll
    for (int kc = 0; kc < 8; ++kc) {
      bfrag k0 = *(const bfrag*)&sm.a.Ks[lane16][kc * 32 + quad * 8];
      bfrag k1 = *(const bfrag*)&sm.a.Ks[16 + lane16][kc * 32 + quad * 8];
      s[0] = __builtin_amdgcn_mfma_f32_16x16x32_bf16(qf[kc], k0, s[0], 0, 0, 0);
      s[1] = __builtin_amdgcn_mfma_f32_16x16x32_bf16(qf[kc], k1, s[1], 0, 0, 0);
    }

    // fixed-max softmax: p = exp(s*scale); lane-partial row sums; P -> LDS
#pragma unroll
    for (int tt = 0; tt < 2; ++tt)
#pragma unroll
      for (int r = 0; r < 4; ++r) {
        float p = __expf(s[tt][r] * scale);
        lsum[r] += p;
        sm.a.Ps[w][quad * 4 + r][tt * 16 + lane16] = f2bf(p);
      }
    // NO barrier: Ps[w] is wave-private; in-wave LDS ordering suffices

    // O += P V  (one 32-key MFMA step, 16 d-tiles)
    bfrag pf = *(const bfrag*)&sm.a.Ps[w][lane16][quad * 8];
#pragma unroll
    for (int dt = 0; dt < 16; ++dt) {
      bfrag vf = *(const bfrag*)&sm.a.Vs[dt * 16 + lane16][quad * 8];
      o[dt] = __builtin_amdgcn_mfma_f32_16x16x32_bf16(pf, vf, o[dt], 0, 0, 0);
    }
  }

  // row-sum reduction (once): 16-lane butterfly within quad groups
#pragma unroll
  for (int r = 0; r < 4; ++r) {
#pragma unroll
    for (int off = 1; off < 16; off <<= 1)
      lsum[r] += __shfl_xor(lsum[r], off, 64);
  }
  if (lane16 == 0) {
#pragma unroll
    for (int r = 0; r < 4; ++r)
      Lpart[((size_t)z * BN + b) * ND + q0 + w * 16 + quad * 4 + r] = lsum[r];
  }

  __syncthreads();
  // unnormalized O -> transposed bf16 staging ot[d][q_local]
#pragma unroll
  for (int dt = 0; dt < 16; ++dt)
#pragma unroll
    for (int r = 0; r < 4; ++r)
      sm.ot[dt * 16 + lane16][w * 16 + quad * 4 + r] = f2bf(o[dt][r]);
  __syncthreads();
  u16* Op = (z == 0) ? O0 : O1;
#pragma unroll
  for (int it = 0; it < 8; ++it) {
    int c = it * 256 + t;
    int d = c >> 3, co = (c & 7) * 8;
    size_t g = ((size_t)b * CD + d) * ND + q0 + co;
    *(uint4*)(Op + g) = *(const uint4*)&sm.ot[d][co];
  }
}

// ---------- combine partials + residual: out = x + (O0+O1)/(l0+l1) ----------
__global__ __launch_bounds__(256) void k_combine(
    const u16* __restrict__ O0, const u16* __restrict__ O1,
    const float* __restrict__ L, const float* __restrict__ x,
    float* __restrict__ out) {
  size_t e = ((size_t)blockIdx.x * 256 + threadIdx.x) * 8;
  int n = (int)(e & (ND - 1));
  int b = (int)(e >> 20);  // C*N = 2^20
  size_t ln = (size_t)b * ND + n;
  float4 la0 = *(const float4*)(L + ln);
  float4 la1 = *(const float4*)(L + ln + 4);
  float4 lb0 = *(const float4*)(L + (size_t)BN * ND + ln);
  float4 lb1 = *(const float4*)(L + (size_t)BN * ND + ln + 4);
  union { uint4 q; u16 s[8]; } u0, u1;
  u0.q = *(const uint4*)(O0 + e);
  u1.q = *(const uint4*)(O1 + e);
  float4 x0 = *(const float4*)(x + e);
  float4 x1 = *(const float4*)(x + e + 4);
  float inv0 = 1.f / (la0.x + lb0.x), inv1 = 1.f / (la0.y + lb0.y);
  float inv2 = 1.f / (la0.z + lb0.z), inv3 = 1.f / (la0.w + lb0.w);
  float inv4 = 1.f / (la1.x + lb1.x), inv5 = 1.f / (la1.y + lb1.y);
  float inv6 = 1.f / (la1.z + lb1.z), inv7 = 1.f / (la1.w + lb1.w);
  float4 r0, r1;
  r0.x = x0.x + (bf2f(u0.s[0]) + bf2f(u1.s[0])) * inv0;
  r0.y = x0.y + (bf2f(u0.s[1]) + bf2f(u1.s[1])) * inv1;
  r0.z = x0.z + (bf2f(u0.s[2]) + bf2f(u1.s[2])) * inv2;
  r0.w = x0.w + (bf2f(u0.s[3]) + bf2f(u1.s[3])) * inv3;
  r1.x = x1.x + (bf2f(u0.s[4]) + bf2f(u1.s[4])) * inv4;
  r1.y = x1.y + (bf2f(u0.s[5]) + bf2f(u1.s[5])) * inv5;
  r1.z = x1.z + (bf2f(u0.s[6]) + bf2f(u1.s[6])) * inv6;
  r1.w = x1.w + (bf2f(u0.s[7]) + bf2f(u1.s[7])) * inv7;
  *(float4*)(out + e) = r0;
  *(float4*)(out + e + 4) = r1;
}

extern "C" void kernel_launch(void* const* d_in, const int* in_sizes, int n_in,
                              void* d_out, int out_size, void* d_ws, size_t ws_size,
                              hipStream_t stream) {
  const float* x  = (const float*)d_in[0];
  const float* y  = (const float*)d_in[1];
  const float* Wq = (const float*)d_in[2];
  const float* bq = (const float*)d_in[3];
  const float* Wk = (const float*)d_in[4];
  const float* bk = (const float*)d_in[5];
  const float* Wv = (const float*)d_in[6];
  const float* bv = (const float*)d_in[7];
  float* out = (float*)d_out;
  u16* ws = (u16*)d_ws;
  const size_t WSZ = (size_t)3 * CD * CD;   // bf16 weights
  const size_t SZ  = (size_t)BN * ND * CD;  // 4,194,304 elems per tensor
  u16* wB = ws;
  u16* xT = ws + WSZ;
  u16* yT = xT + SZ;
  u16* Qb = yT + SZ;
  u16* Kb = Qb + SZ;
  u16* Vb = Kb + SZ;
  // dead-region reuse after projections: partial O over xT/yT, L over wq
  u16* O0 = xT;
  u16* O1 = yT;
  float* Lp = (float*)ws;  // 2*B*N floats = 128 KB, overlays wq (dead by then)

  k_cvtW<<<dim3(64, 3), 256, 0, stream>>>(Wq, Wk, Wv, wB);
  k_transpose<<<dim3(ND / 64, CD / 64, BN * 2), 256, 0, stream>>>(x, y, xT, yT);
  // merged Q+K projection: z=0 -> (xT, Wq, bq, Qb); z=1 -> (yT, Wk, bk, Kb)
  k_proj<<<dim3(BN * ND / 64, CD / 64, 2), 256, 0, stream>>>(
      xT, wB, bq, bk, Qb, CD, 0, SZ, (size_t)CD * CD, SZ);
  // V projection (transposed output): [B][C][N]
  k_proj<<<dim3(CD / 64, ND / 64, BN), 256, 0, stream>>>(
      wB + (size_t)2 * CD * CD, yT, bv, bv, Vb, ND, 1,
      (size_t)0, (size_t)ND * CD, (size_t)CD * ND);
  k_attn<<<dim3(ND / 64, BN, NSPLIT), 256, 0, stream>>>(Qb, Kb, Vb, O0, O1, Lp);
  k_combine<<<dim3((BN * CD * ND) / (256 * 8)), 256, 0, stream>>>(O0, O1, Lp, x, out);
}

// Round 5
// 206.772 us; speedup vs baseline: 3.4916x; 2.3682x over previous
//
#include <hip/hip_runtime.h>
#include <stdint.h>

#define BN 4
#define CD 256
#define ND 4096
#define NK 32            // key-tile size in attention

typedef unsigned short u16;
typedef short bfrag __attribute__((ext_vector_type(8)));  // 8 bf16 = 4 VGPR
typedef float ffrag __attribute__((ext_vector_type(4)));  // MFMA C/D frag

__device__ __forceinline__ float bf2f(u16 u) {
  union { unsigned int i; float f; } v;
  v.i = ((unsigned int)u) << 16;
  return v.f;
}
__device__ __forceinline__ u16 f2bf(float f) {
  union { float f; unsigned int i; } v;
  v.f = f;
  return (u16)((v.i + 0x7FFFu + ((v.i >> 16) & 1u)) >> 16);  // RNE
}
// async global->LDS DMA, 16B per lane; LDS dest = wave-uniform base + lane*16
__device__ __forceinline__ void gload_lds(const u16* g, u16* l) {
  __builtin_amdgcn_global_load_lds(
      (const __attribute__((address_space(1))) void*)g,
      (__attribute__((address_space(3))) void*)l, 16, 0, 0);
}

// ---------- convert fp32 weights [256][256] x3 -> bf16 ----------
__global__ __launch_bounds__(256) void k_cvtW(
    const float* __restrict__ Wq, const float* __restrict__ Wk,
    const float* __restrict__ Wv, u16* __restrict__ wb) {
  int m = blockIdx.y;
  const float* src = (m == 0) ? Wq : ((m == 1) ? Wk : Wv);
  u16* dst = wb + (size_t)m * CD * CD;
  int i = (blockIdx.x * 256 + threadIdx.x) * 4;
  float4 v = *(const float4*)(src + i);
  ushort4 o;
  o.x = f2bf(v.x); o.y = f2bf(v.y); o.z = f2bf(v.z); o.w = f2bf(v.w);
  *(ushort4*)(dst + i) = o;
}

// ---------- transpose+cast [B][C][N] fp32 -> [B][N][C] bf16 ----------
__global__ __launch_bounds__(256) void k_transpose(
    const float* __restrict__ x, const float* __restrict__ y,
    u16* __restrict__ xT, u16* __restrict__ yT) {
  __shared__ alignas(16) u16 tile[64][72];
  int n0 = blockIdx.x * 64, c0 = blockIdx.y * 64, bz = blockIdx.z;
  const float* src = (bz < BN) ? x : y;
  u16* dst = (bz < BN) ? xT : yT;
  int b = bz & (BN - 1);
  src += (size_t)b * CD * ND;
  dst += (size_t)b * ND * CD;
  int t = threadIdx.x;
#pragma unroll
  for (int it = 0; it < 4; ++it) {
    int idx = it * 256 + t;
    int ci = idx >> 4;
    int nj = (idx & 15) * 4;
    float4 v = *(const float4*)(src + (size_t)(c0 + ci) * ND + n0 + nj);
    tile[nj + 0][ci] = f2bf(v.x);
    tile[nj + 1][ci] = f2bf(v.y);
    tile[nj + 2][ci] = f2bf(v.z);
    tile[nj + 3][ci] = f2bf(v.w);
  }
  __syncthreads();
#pragma unroll
  for (int it = 0; it < 2; ++it) {
    int idx = it * 256 + t;
    int ni = idx >> 3;
    int cj = (idx & 7) * 8;
    uint4 v = *(const uint4*)&tile[ni][cj];
    *(uint4*)(dst + (size_t)(n0 + ni) * CD + c0 + cj) = v;
  }
}

// ---------- projection GEMM (bf16 in/out, fp32 bias) ----------
__global__ __launch_bounds__(256, 2) void k_proj(
    const u16* __restrict__ A, const u16* __restrict__ Bw,
    const float* __restrict__ biasA, const float* __restrict__ biasB,
    u16* __restrict__ C, int ldc, int bias_per_row,
    size_t aBS, size_t bBS, size_t cBS) {
  __shared__ alignas(16) u16 As[64][264];
  __shared__ alignas(16) u16 Bs[64][136];
  int m0 = blockIdx.x * 64, n0 = blockIdx.y * 64;
  size_t z = blockIdx.z;
  const float* bias = (z == 0) ? biasA : biasB;
  A += z * aBS; Bw += z * bBS; C += z * cBS;
  int t = threadIdx.x, w = t >> 6, l = t & 63;
  int lane16 = l & 15, quad = l >> 4;
#pragma unroll
  for (int it = 0; it < 8; ++it) {
    int c = it * 256 + t;
    int r = c >> 5, co = (c & 31) * 8;
    *(uint4*)&As[r][co] = *(const uint4*)(A + (size_t)(m0 + r) * CD + co);
  }
  ffrag acc[4];
#pragma unroll
  for (int tt = 0; tt < 4; ++tt) acc[tt] = ffrag{0.f, 0.f, 0.f, 0.f};
#pragma unroll
  for (int half = 0; half < 2; ++half) {
    if (half) __syncthreads();
#pragma unroll
    for (int it = 0; it < 4; ++it) {
      int c = it * 256 + t;
      int r = c >> 4, co = (c & 15) * 8;
      *(uint4*)&Bs[r][co] =
          *(const uint4*)(Bw + (size_t)(n0 + r) * CD + half * 128 + co);
    }
    __syncthreads();
#pragma unroll
    for (int kc = 0; kc < 4; ++kc) {
      bfrag af = *(const bfrag*)&As[w * 16 + lane16][half * 128 + kc * 32 + quad * 8];
#pragma unroll
      for (int tt = 0; tt < 4; ++tt) {
        bfrag bfr = *(const bfrag*)&Bs[tt * 16 + lane16][kc * 32 + quad * 8];
        acc[tt] = __builtin_amdgcn_mfma_f32_16x16x32_bf16(af, bfr, acc[tt], 0, 0, 0);
      }
    }
  }
#pragma unroll
  for (int tt = 0; tt < 4; ++tt) {
    int col = n0 + tt * 16 + lane16;
    float bcol = bias_per_row ? 0.f : bias[col];
#pragma unroll
    for (int r = 0; r < 4; ++r) {
      int row = m0 + w * 16 + quad * 4 + r;
      float bb = bias_per_row ? bias[row] : bcol;
      C[(size_t)row * ldc + col] = f2bf(acc[tt][r] + bb);
    }
  }
}

// ---------- flash attention, split-K, async-DMA double-buffered ----------
// Q,K: [B*N][C]; Vt: [B][C][N]. 128 q-rows/block, 4 waves x 2 m-tiles.
// One __syncthreads per K-tile. XOR-swizzled unpadded LDS (global_load_lds).
union SmemU {
  struct {
    u16 Ks[2][NK][256];   // 32,768 B  chunk^=(row&7) swizzle
    u16 Vs[2][CD][NK];    // 32,768 B  chunk^=((d>>1)&3) swizzle
    u16 Ps[8][16][40];    // 10,240 B  wave-private P staging
  } a;                     // 75,776 B
  u16 ot[CD][136];         // 69,632 B  epilogue O^T staging
};

template <int NS>
__global__ __launch_bounds__(256, 2) void k_attn(
    const u16* __restrict__ Q, const u16* __restrict__ K,
    const u16* __restrict__ Vt, u16* __restrict__ O01,
    u16* __restrict__ O23, float* __restrict__ Lpart) {
  constexpr int NIT = ND / NS / NK;
  __shared__ alignas(16) SmemU sm;
  int b = blockIdx.y, q0 = blockIdx.x * 128, z = blockIdx.z;
  int t = threadIdx.x, w = t >> 6, l = t & 63;
  int lane16 = l & 15, quad = l >> 4;
  const float scale = 0.0625f;  // 256^-0.5

  // Q frags: A-layout rows q0 + (w*2+mi)*16 + lane16
  bfrag qf[2][8];
#pragma unroll
  for (int mi = 0; mi < 2; ++mi) {
    const u16* Qrow =
        Q + ((size_t)b * ND + q0 + (w * 2 + mi) * 16 + lane16) * CD;
#pragma unroll
    for (int kc = 0; kc < 8; ++kc)
      qf[mi][kc] = *(const bfrag*)(Qrow + kc * 32 + quad * 8);
  }

  ffrag o[2][16];
#pragma unroll
  for (int mi = 0; mi < 2; ++mi)
#pragma unroll
    for (int i = 0; i < 16; ++i) o[mi][i] = ffrag{0.f, 0.f, 0.f, 0.f};
  float lsum[2][4] = {{0.f, 0.f, 0.f, 0.f}, {0.f, 0.f, 0.f, 0.f}};

  const u16* Kb = K + ((size_t)b * ND + z * (ND / NS)) * CD;
  const u16* Vb = Vt + (size_t)b * CD * ND + z * (ND / NS);

  auto stage = [&](int kt2) {
    int dbuf = kt2 & 1;
    const u16* Kt = Kb + (size_t)kt2 * NK * CD;
    const u16* Vtt = Vb + kt2 * NK;
#pragma unroll
    for (int p = 0; p < 4; ++p) {
      int r = p * 8 + w * 2 + (l >> 5);
      int j = (l & 31) ^ (r & 7);
      gload_lds(Kt + (size_t)r * CD + j * 8, &sm.a.Ks[dbuf][p * 8 + w * 2][0]);
    }
#pragma unroll
    for (int p = 0; p < 4; ++p) {
      int dd = p * 64 + w * 16 + (l >> 2);
      int j = (l & 3) ^ ((dd >> 1) & 3);
      gload_lds(Vtt + (size_t)dd * ND + j * 8, &sm.a.Vs[dbuf][p * 64 + w * 16][0]);
    }
  };

  stage(0);
  for (int kt = 0; kt < NIT; ++kt) {
    int dbuf = kt & 1;
    __syncthreads();  // drains DMA for buf dbuf; recycling of dbuf^1 is safe
    if (kt + 1 < NIT) stage(kt + 1);  // async into other buffer, no wait

    // S = Q K^T  (2 m-tiles x 2 key-tiles)
    ffrag s2[2][2];
#pragma unroll
    for (int mi = 0; mi < 2; ++mi)
#pragma unroll
      for (int tt = 0; tt < 2; ++tt) s2[mi][tt] = ffrag{0.f, 0.f, 0.f, 0.f};
#pragma unroll
    for (int kc = 0; kc < 8; ++kc) {
      bfrag kf0, kf1;
      {
        int r = lane16;
        int cp = (kc * 4 + quad) ^ (r & 7);
        kf0 = *(const bfrag*)&sm.a.Ks[dbuf][r][cp * 8];
        int r1 = 16 + lane16;
        int cp1 = (kc * 4 + quad) ^ (r1 & 7);
        kf1 = *(const bfrag*)&sm.a.Ks[dbuf][r1][cp1 * 8];
      }
#pragma unroll
      for (int mi = 0; mi < 2; ++mi) {
        s2[mi][0] = __builtin_amdgcn_mfma_f32_16x16x32_bf16(qf[mi][kc], kf0,
                                                            s2[mi][0], 0, 0, 0);
        s2[mi][1] = __builtin_amdgcn_mfma_f32_16x16x32_bf16(qf[mi][kc], kf1,
                                                            s2[mi][1], 0, 0, 0);
      }
    }

    // fixed-max softmax: p = exp(s*scale); lane-partial sums; P -> LDS
#pragma unroll
    for (int mi = 0; mi < 2; ++mi)
#pragma unroll
      for (int tt = 0; tt < 2; ++tt)
#pragma unroll
        for (int r = 0; r < 4; ++r) {
          float p = __expf(s2[mi][tt][r] * scale);
          lsum[mi][r] += p;
          sm.a.Ps[w * 2 + mi][quad * 4 + r][tt * 16 + lane16] = f2bf(p);
        }
    // wave-private Ps: in-wave LDS ordering suffices, no barrier
    bfrag pf0 = *(const bfrag*)&sm.a.Ps[w * 2 + 0][lane16][quad * 8];
    bfrag pf1 = *(const bfrag*)&sm.a.Ps[w * 2 + 1][lane16][quad * 8];

    // O += P V  (16 d-tiles, V-frag shared across both m-tiles)
#pragma unroll
    for (int dt = 0; dt < 16; ++dt) {
      int dd = dt * 16 + lane16;
      int cp = quad ^ ((dd >> 1) & 3);
      bfrag vf = *(const bfrag*)&sm.a.Vs[dbuf][dd][cp * 8];
      o[0][dt] = __builtin_amdgcn_mfma_f32_16x16x32_bf16(pf0, vf, o[0][dt], 0, 0, 0);
      o[1][dt] = __builtin_amdgcn_mfma_f32_16x16x32_bf16(pf1, vf, o[1][dt], 0, 0, 0);
    }
  }

  // row-sum reduction: 16-lane butterfly within quad groups, once
#pragma unroll
  for (int mi = 0; mi < 2; ++mi)
#pragma unroll
    for (int r = 0; r < 4; ++r) {
#pragma unroll
      for (int off = 1; off < 16; off <<= 1)
        lsum[mi][r] += __shfl_xor(lsum[mi][r], off, 64);
    }
  if (lane16 == 0) {
#pragma unroll
    for (int mi = 0; mi < 2; ++mi)
#pragma unroll
      for (int r = 0; r < 4; ++r)
        Lpart[((size_t)z * BN + b) * ND + q0 + (w * 2 + mi) * 16 + quad * 4 + r] =
            lsum[mi][r];
  }

  __syncthreads();
  // unnormalized O -> transposed bf16 staging ot[d][q_local]
#pragma unroll
  for (int mi = 0; mi < 2; ++mi)
#pragma unroll
    for (int dt = 0; dt < 16; ++dt)
#pragma unroll
      for (int r = 0; r < 4; ++r)
        sm.ot[dt * 16 + lane16][(w * 2 + mi) * 16 + quad * 4 + r] =
            f2bf(o[mi][dt][r]);
  __syncthreads();
  const size_t SZc = (size_t)BN * ND * CD;
  u16* Op = ((z < 2) ? O01 : O23) + (size_t)(z & 1) * SZc;
#pragma unroll
  for (int it = 0; it < 16; ++it) {
    int c = it * 256 + t;
    int dd = c >> 4, co = (c & 15) * 8;
    size_t g = ((size_t)b * CD + dd) * ND + q0 + co;
    *(uint4*)(Op + g) = *(const uint4*)&sm.ot[dd][co];
  }
}

// ---------- combine partials + residual ----------
template <int NS>
__global__ __launch_bounds__(256) void k_combine(
    const u16* __restrict__ O01, const u16* __restrict__ O23,
    const float* __restrict__ L, const float* __restrict__ x,
    float* __restrict__ out) {
  const size_t SZc = (size_t)BN * ND * CD;
  size_t e = ((size_t)blockIdx.x * 256 + threadIdx.x) * 8;
  int n = (int)(e & (ND - 1));
  int b = (int)(e >> 20);  // C*N = 2^20
  float ls[8] = {0, 0, 0, 0, 0, 0, 0, 0};
  float acc[8] = {0, 0, 0, 0, 0, 0, 0, 0};
#pragma unroll
  for (int z = 0; z < NS; ++z) {
    const float* Lr = L + ((size_t)z * BN + b) * ND + n;
    float4 l0 = *(const float4*)(Lr);
    float4 l1 = *(const float4*)(Lr + 4);
    ls[0] += l0.x; ls[1] += l0.y; ls[2] += l0.z; ls[3] += l0.w;
    ls[4] += l1.x; ls[5] += l1.y; ls[6] += l1.z; ls[7] += l1.w;
    const u16* Oz = ((z < 2) ? O01 : O23) + (size_t)(z & 1) * SZc + e;
    union { uint4 q; u16 s[8]; } u;
    u.q = *(const uint4*)Oz;
#pragma unroll
    for (int j = 0; j < 8; ++j) acc[j] += bf2f(u.s[j]);
  }
  float4 x0 = *(const float4*)(x + e);
  float4 x1 = *(const float4*)(x + e + 4);
  float4 r0, r1;
  r0.x = x0.x + acc[0] / ls[0];
  r0.y = x0.y + acc[1] / ls[1];
  r0.z = x0.z + acc[2] / ls[2];
  r0.w = x0.w + acc[3] / ls[3];
  r1.x = x1.x + acc[4] / ls[4];
  r1.y = x1.y + acc[5] / ls[5];
  r1.z = x1.z + acc[6] / ls[6];
  r1.w = x1.w + acc[7] / ls[7];
  *(float4*)(out + e) = r0;
  *(float4*)(out + e + 4) = r1;
}

extern "C" void kernel_launch(void* const* d_in, const int* in_sizes, int n_in,
                              void* d_out, int out_size, void* d_ws, size_t ws_size,
                              hipStream_t stream) {
  const float* x  = (const float*)d_in[0];
  const float* y  = (const float*)d_in[1];
  const float* Wq = (const float*)d_in[2];
  const float* bq = (const float*)d_in[3];
  const float* Wk = (const float*)d_in[4];
  const float* bk = (const float*)d_in[5];
  const float* Wv = (const float*)d_in[6];
  const float* bv = (const float*)d_in[7];
  float* out = (float*)d_out;
  u16* ws = (u16*)d_ws;
  const size_t WSZ = (size_t)3 * CD * CD;
  const size_t SZ  = (size_t)BN * ND * CD;
  u16* wB = ws;
  u16* xT = ws + WSZ;
  u16* yT = xT + SZ;
  u16* Qb = yT + SZ;
  u16* Kb = Qb + SZ;
  u16* Vb = Kb + SZ;
  u16* O23 = Vb + SZ;      // 2 more partials (NSPLIT=4 path only)
  u16* O01 = xT;           // z=0,1 partials over dead xT,yT (contiguous)
  float* Lp = (float*)ws;  // <=256 KB over dead wB (384 KB)
  const size_t need4 = (WSZ + 7 * SZ) * sizeof(u16);  // 59.1 MB
  const bool big = ws_size >= need4;                  // constant across calls
  const int cgrid = (int)(SZ / (256 * 8));            // 2048 blocks (out = SZ floats)

  k_cvtW<<<dim3(64, 3), 256, 0, stream>>>(Wq, Wk, Wv, wB);
  k_transpose<<<dim3(ND / 64, CD / 64, BN * 2), 256, 0, stream>>>(x, y, xT, yT);
  k_proj<<<dim3(BN * ND / 64, CD / 64, 2), 256, 0, stream>>>(
      xT, wB, bq, bk, Qb, CD, 0, SZ, (size_t)CD * CD, SZ);
  k_proj<<<dim3(CD / 64, ND / 64, BN), 256, 0, stream>>>(
      wB + (size_t)2 * CD * CD, yT, bv, bv, Vb, ND, 1,
      (size_t)0, (size_t)ND * CD, (size_t)CD * ND);
  if (big) {
    k_attn<4><<<dim3(ND / 128, BN, 4), 256, 0, stream>>>(Qb, Kb, Vb, O01, O23, Lp);
    k_combine<4><<<dim3(cgrid), 256, 0, stream>>>(O01, O23, Lp, x, out);
  } else {
    k_attn<2><<<dim3(ND / 128, BN, 2), 256, 0, stream>>>(Qb, Kb, Vb, O01, O01, Lp);
    k_combine<2><<<dim3(cgrid), 256, 0, stream>>>(O01, O01, Lp, x, out);
  }
}